// Round 2
// baseline (2144.190 us; speedup 1.0000x reference)
//
#include <hip/hip_runtime.h>
#include <hip/hip_bf16.h>
#include <hip/hip_fp16.h>

#define NB 128
#define TT 4096
#define HH 256
#define G3 768
#define STEPW 5
#define PI_F 3.14159265358979323846f
#define D2R  0.017453292519943295f

typedef _Float16 f16x8 __attribute__((ext_vector_type(8)));
typedef _Float16 f16x2 __attribute__((ext_vector_type(2)));
typedef __attribute__((ext_vector_type(4))) float f32x4;

__device__ __forceinline__ unsigned int pack_f16(float x, float y){
  union { f16x2 h; unsigned int u; } cv;
  cv.h = (f16x2){(_Float16)x, (_Float16)y};
  return cv.u;
}

// f32 += f16x2 . f16x2  (v_dot2_f32_f16, f32 accumulate)
__device__ __forceinline__ float dot2h(unsigned int a, unsigned int b, float c){
  union { unsigned int u; f16x2 h; } ua, ub;
  ua.u = a; ub.u = b;
  return __builtin_amdgcn_fdot2(ua.h, ub.h, c, false);
}

// ---------------- setup: per-sample params + prefix sum ----------------
__global__ void k_setup(const float* __restrict__ traj, const int* __restrict__ lens,
                        int* offs, int* rmod, float* cB, float* sB,
                        float* oxB, float* oyB, float* hdB){
  int b = threadIdx.x;
  if (b < NB) {
    int L = lens[b];
    rmod[b] = L % STEPW;
    const float* last = traj + ((size_t)b*TT + (size_t)(L-1))*3;
    float ox = last[0], oy = last[1], hd = -last[2];
    float th = hd * D2R;
    cB[b] = cosf(th); sB[b] = sinf(th);
    oxB[b]=ox; oyB[b]=oy; hdB[b]=hd;
  }
  __syncthreads();
  if (threadIdx.x == 0) {
    int acc = 0;
    for (int i=0;i<NB;i++){ offs[i]=acc; acc += lens[i]/STEPW; }
    offs[NB]=acc;
  }
}

// ---------------- prep: f16 weight repacks ----------------
// w2h[o][tap][ch] = w2[o][ch][tap]   (B^T layout for conv2 GEMM)
// wihh[g][ch]     = w_ih[g][ch]      (already B^T layout)
__global__ void k_prep(const float* __restrict__ w2, const float* __restrict__ wih,
                       _Float16* w2h, _Float16* wihh){
  int i = blockIdx.x*256 + threadIdx.x;      // 0 .. 196607
  int o = i / 768; int rem = i - o*768;
  int tap = rem >> 8; int ch = rem & 255;
  w2h[i]  = (_Float16)w2[o*768 + ch*3 + tap];
  wihh[i] = (_Float16)wih[i];
}

// ---------------- fused rotate + conv1 + conv2(MFMA) + mean + gx(MFMA) ----------------
__launch_bounds__(256)
__global__ void k_conv(const float* __restrict__ traj, const int* __restrict__ offs,
                       const int* __restrict__ rmod,
                       const float* __restrict__ cB, const float* __restrict__ sB,
                       const float* __restrict__ oxB, const float* __restrict__ oyB,
                       const float* __restrict__ hdB,
                       const float* __restrict__ w1, const float* __restrict__ b1,
                       const float* __restrict__ b2,
                       const _Float16* __restrict__ w2h,
                       const _Float16* __restrict__ wihh,
                       _Float16* __restrict__ gx, int N)
{
  __shared__ __align__(16) union {
    _Float16 y1p[16][7][264];                  // 59,136 B (pad 264: row stride 528 B, 16B-aligned)
    struct { float ar[16][264]; _Float16 arb[16][264]; } p2;
  } U;
  __shared__ float xls[16][5][3];
  __shared__ int   segB[16], segT0[16];
  __shared__ float segC[16], segS[16], segOx[16], segOy[16], segHd[16];

  const int tid = threadIdx.x;
  const int n0  = blockIdx.x * 16;
  const int cnt = min(16, N - n0);

  { uint4* z = (uint4*)&U.y1p[0][0][0];              // zero incl. pad columns wp=0,6
    for (int i = tid; i < 3696; i += 256) z[i] = make_uint4(0,0,0,0); }

  if (tid < 16) {
    int n = n0 + min(tid, cnt-1);
    int lo=0, hi=NB-1;
    while (lo < hi) { int mid=(lo+hi+1)>>1; if (offs[mid] <= n) lo=mid; else hi=mid-1; }
    int b = lo; int k = n - offs[b];
    segB[tid]=b; segT0[tid]= rmod[b] + STEPW*k;
    segC[tid]=cB[b]; segS[tid]=sB[b]; segOx[tid]=oxB[b]; segOy[tid]=oyB[b]; segHd[tid]=hdB[b];
  }
  __syncthreads();

  // rotate the 16x5 window points
  if (tid < 80) {
    int s = tid/5, w = tid%5;
    int b = segB[s]; int t = segT0[s] + w;
    const float* p = traj + ((size_t)b*TT + (size_t)t)*3;
    float X=p[0], Y=p[1], A=p[2];
    float dx = X - segOx[s], dy = Y - segOy[s];
    float c = segC[s], sn = segS[s];
    float ang = fmodf(A + segHd[s] + 720.0f, 360.0f) * D2R;
    if (ang > PI_F) ang -= 2.0f*PI_F;
    xls[s][w][0] = c*dx - sn*dy;
    xls[s][w][1] = sn*dx + c*dy;
    xls[s][w][2] = ang;
  }
  __syncthreads();

  // conv1: thread = out channel, zero-pad relative to 5-window
  {
    int o = tid;
    float wv[3][3];
    #pragma unroll
    for (int i2=0;i2<3;i2++)
      #pragma unroll
      for (int tp=0;tp<3;tp++) wv[i2][tp] = w1[o*9 + i2*3 + tp];
    float bb = b1[o];
    for (int s=0;s<16;s++)
      #pragma unroll
      for (int w=0;w<5;w++) {
        float acc = bb;
        #pragma unroll
        for (int tp=0;tp<3;tp++) {
          int wp = w + tp - 1;
          if (wp >= 0 && wp < 5)
            acc += xls[s][wp][0]*wv[0][tp] + xls[s][wp][1]*wv[1][tp] + xls[s][wp][2]*wv[2][tp];
        }
        U.y1p[s][w+1][o] = (_Float16)fmaxf(acc, 0.0f);
      }
  }
  __syncthreads();

  // conv2 as GEMM: rows=(seg,w) 80, cols=256 out-ch, K=768=(tap,ch)
  const int wv_  = tid >> 6;          // wave 0..3
  const int lane = tid & 63;
  const int m = lane & 15, q = lane >> 4;
  f32x4 acc[5][4];
  #pragma unroll
  for (int a=0;a<5;a++) for (int b_=0;b_<4;b_++) acc[a][b_] = (f32x4){0.f,0.f,0.f,0.f};
  int segi[5], wwi[5];
  #pragma unroll
  for (int mt=0; mt<5; mt++){ int row = mt*16+m; segi[mt]=row/5; wwi[mt]=row%5; }

  for (int ks=0; ks<24; ks++) {
    int tap = ks >> 3, ch0 = (ks & 7)*32 + q*8;
    f16x8 afr[5];
    #pragma unroll
    for (int mt=0; mt<5; mt++)
      afr[mt] = *(const f16x8*)&U.y1p[segi[mt]][wwi[mt]+tap][ch0];
    int kq = ks*32 + q*8;
    #pragma unroll
    for (int nn=0; nn<4; nn++) {
      int col = (wv_*4+nn)*16 + m;
      f16x8 bfr = *(const f16x8*)(w2h + (size_t)col*768 + kq);
      #pragma unroll
      for (int mt=0; mt<5; mt++)
        acc[mt][nn] = __builtin_amdgcn_mfma_f32_16x16x32_f16(afr[mt], bfr, acc[mt][nn], 0,0,0);
    }
  }
  __syncthreads();

  // mean over w (sum via LDS atomics), +bias, relu
  { float* arz = &U.p2.ar[0][0];
    for (int i=tid;i<16*264;i+=256) arz[i]=0.f; }
  __syncthreads();
  #pragma unroll
  for (int nn=0;nn<4;nn++){
    int col = (wv_*4+nn)*16 + m;
    float bias = b2[col];
    #pragma unroll
    for (int mt=0;mt<5;mt++){
      #pragma unroll
      for (int v=0;v<4;v++){
        int row = mt*16 + q*4 + v;
        float val = fmaxf(acc[mt][nn][v] + bias, 0.f);
        atomicAdd(&U.p2.ar[row/5][col], val);
      }
    }
  }
  __syncthreads();
  for (int i=tid; i<16*256; i+=256){
    int s=i>>8, c2=i&255;
    U.p2.arb[s][c2] = (_Float16)(U.p2.ar[s][c2]*0.2f);
  }
  __syncthreads();

  // gx GEMM: M=16 segs, N=768 gates, K=256
  f32x4 acc2[12];
  #pragma unroll
  for (int a=0;a<12;a++) acc2[a] = (f32x4){0.f,0.f,0.f,0.f};
  #pragma unroll
  for (int ks=0; ks<8; ks++) {
    int ch0 = ks*32 + q*8;
    f16x8 afr = *(const f16x8*)&U.p2.arb[m][ch0];
    #pragma unroll
    for (int nn=0; nn<12; nn++) {
      int col = (wv_*12+nn)*16 + m;
      f16x8 bfr = *(const f16x8*)(wihh + (size_t)col*256 + ch0);
      acc2[nn] = __builtin_amdgcn_mfma_f32_16x16x32_f16(afr, bfr, acc2[nn], 0,0,0);
    }
  }
  #pragma unroll
  for (int nn=0; nn<12; nn++){
    int col = (wv_*12+nn)*16 + m;
    #pragma unroll
    for (int v=0; v<4; v++){
      int row = q*4 + v;            // C row = seg index (single M-tile)
      if (row < cnt)
        gx[(size_t)(n0+row)*G3 + col] = (_Float16)acc2[nn][v];
    }
  }
}

// ---------------- GRU recurrence: 1 block / sample, weights in VGPRs (f16) ----------------
__launch_bounds__(768)
__global__ void k_gru(const _Float16* __restrict__ gx,
                      const float* __restrict__ whh,
                      const float* __restrict__ bih, const float* __restrict__ bhh,
                      const int* __restrict__ offs, float* __restrict__ out)
{
  __shared__ float sArr[G3];            // rows<512: gx+bih+gh+bhh ; rows>=512: gh+bhh
  __shared__ float sxArr[HH];           // xn part for n-rows
  __shared__ float hf[HH];              // h carried in f32
  __shared__ __align__(16) unsigned int hb[HH/2];  // h as packed f16 pairs

  const int tid = threadIdx.x;          // = gate row 0..767
  const int b = blockIdx.x;
  const int base = offs[b];
  const int segs = offs[b+1] - base;

  // own row of w_hh -> 128 packed f16 pairs in registers
  unsigned int wpk[128];
  {
    const float4* wr = (const float4*)(whh + (size_t)tid*256);
    #pragma unroll
    for (int c=0;c<64;c++){
      float4 v = wr[c];
      wpk[2*c]   = pack_f16(v.x, v.y);
      wpk[2*c+1] = pack_f16(v.z, v.w);
    }
  }
  const float bih_own = bih[tid];
  const float bhh_own = bhh[tid];

  if (tid < HH) hf[tid] = 0.f;
  if (tid < HH/2) hb[tid] = 0u;
  __syncthreads();

  float gxv = (float)gx[(size_t)base*G3 + tid];   // j=0 row, preloaded
  for (int j=0; j<segs; j++) {
    const size_t nrow = (size_t)(base + j);
    // prefetch next row's gx so its latency hides under the dot chain
    const int jn = (j+1 < segs) ? j+1 : j;
    float gx_next = (float)gx[(size_t)(base + jn)*G3 + tid];

    float a0=0.f, a1=0.f;
    const uint4* h4 = (const uint4*)hb;
    #pragma unroll
    for (int c=0;c<32;c++){
      uint4 hv = h4[c];
      a0 = dot2h(hv.x, wpk[4*c+0], a0);
      a1 = dot2h(hv.y, wpk[4*c+1], a1);
      a0 = dot2h(hv.z, wpk[4*c+2], a0);
      a1 = dot2h(hv.w, wpk[4*c+3], a1);
    }
    float gf = a0 + a1 + bhh_own;       // gh row (+b_hh)
    if (tid < 512) sArr[tid] = gxv + bih_own + gf;
    else { sArr[tid] = gf; sxArr[tid-512] = gxv + bih_own; }
    __syncthreads();
    if (tid < HH) {
      float r = 1.f/(1.f + __expf(-sArr[tid]));
      float z = 1.f/(1.f + __expf(-sArr[HH+tid]));
      float pre = sxArr[tid] + r*sArr[2*HH+tid];
      float e2 = __expf(2.f*pre);
      float n = 1.f - 2.f/(e2 + 1.f);   // tanh
      float hnew = (1.f-z)*n + z*hf[tid];
      hf[tid] = hnew;
      ((_Float16*)hb)[tid] = (_Float16)hnew;
      out[nrow*HH + tid] = hnew;
    }
    __syncthreads();
    gxv = gx_next;
  }
}

extern "C" void kernel_launch(void* const* d_in, const int* in_sizes, int n_in,
                              void* d_out, int out_size, void* d_ws, size_t ws_size,
                              hipStream_t stream)
{
  const float* traj = (const float*)d_in[0];
  const int*   lens = (const int*)d_in[1];
  const float* w1   = (const float*)d_in[2];
  const float* b1   = (const float*)d_in[3];
  const float* w2   = (const float*)d_in[4];
  const float* b2   = (const float*)d_in[5];
  const float* wih  = (const float*)d_in[6];
  const float* whh  = (const float*)d_in[7];
  const float* bih  = (const float*)d_in[8];
  const float* bhh  = (const float*)d_in[9];
  float* out = (float*)d_out;
  const int N = out_size / HH;

  char* ws = (char*)d_ws;
  int*   offs = (int*)(ws + 0);          // 129 ints
  int*   rmod = (int*)(ws + 1024);
  float* cB   = (float*)(ws + 2048);
  float* sB   = (float*)(ws + 2560);
  float* oxB  = (float*)(ws + 3072);
  float* oyB  = (float*)(ws + 3584);
  float* hdB  = (float*)(ws + 4096);
  _Float16* w2h  = (_Float16*)(ws + 8192);
  _Float16* wihh = (_Float16*)(ws + 8192 + 393216);
  _Float16* gx   = (_Float16*)(ws + 8192 + 2*393216);   // N x 768 f16

  k_setup<<<1, 128, 0, stream>>>(traj, lens, offs, rmod, cB, sB, oxB, oyB, hdB);
  k_prep<<<768, 256, 0, stream>>>(w2, wih, w2h, wihh);
  k_conv<<<(N+15)/16, 256, 0, stream>>>(traj, offs, rmod, cB, sB, oxB, oyB, hdB,
                                        w1, b1, b2, w2h, wihh, gx, N);
  k_gru<<<NB, 768, 0, stream>>>(gx, whh, bih, bhh, offs, out);
}

// Round 3
// 1605.170 us; speedup vs baseline: 1.3358x; 1.3358x over previous
//
#include <hip/hip_runtime.h>
#include <hip/hip_bf16.h>
#include <hip/hip_fp16.h>

#define NB 128
#define TT 4096
#define HH 256
#define G3 768
#define STEPW 5
#define PI_F 3.14159265358979323846f
#define D2R  0.017453292519943295f

typedef _Float16 f16x8 __attribute__((ext_vector_type(8)));
typedef _Float16 f16x2 __attribute__((ext_vector_type(2)));
typedef float f32x4 __attribute__((ext_vector_type(4)));

__device__ __forceinline__ unsigned int pack_f16(float x, float y){
  union { f16x2 h; unsigned int u; } cv;
  cv.h = (f16x2){(_Float16)x, (_Float16)y};
  return cv.u;
}

// f32 += f16x2 . f16x2  (v_dot2_f32_f16)
__device__ __forceinline__ float dot2h(unsigned int a, unsigned int b, float c){
  union { unsigned int u; f16x2 h; } ua, ub;
  ua.u = a; ub.u = b;
  return __builtin_amdgcn_fdot2(ua.h, ub.h, c, false);
}

// ---------------- setup: per-sample params + prefix sum ----------------
__global__ void k_setup(const float* __restrict__ traj, const int* __restrict__ lens,
                        int* offs, int* rmod, float* cB, float* sB,
                        float* oxB, float* oyB, float* hdB){
  __shared__ int sl[NB];
  int b = threadIdx.x;
  if (b < NB) {
    int L = lens[b];
    rmod[b] = L % STEPW;
    sl[b] = L / STEPW;
    const float* last = traj + ((size_t)b*TT + (size_t)(L-1))*3;
    float ox = last[0], oy = last[1], hd = -last[2];
    float th = hd * D2R;
    cB[b] = cosf(th); sB[b] = sinf(th);
    oxB[b]=ox; oyB[b]=oy; hdB[b]=hd;
  }
  __syncthreads();
  if (threadIdx.x == 0) {
    int acc = 0;
    for (int i=0;i<NB;i++){ offs[i]=acc; acc += sl[i]; }
    offs[NB]=acc;
  }
}

// ---------------- prep: f16 weight repacks ----------------
// w2h[o][tap][ch] = w2[o][ch][tap]; wihh[g][ch] = w_ih[g][ch];
// w1h[o][k] : k = tap*3+inch (k<9), zero-padded to 32.
__global__ void k_prep(const float* __restrict__ w2, const float* __restrict__ wih,
                       const float* __restrict__ w1,
                       _Float16* w2h, _Float16* wihh, _Float16* w1h){
  int i = blockIdx.x*256 + threadIdx.x;      // 0 .. 196607
  int o = i / 768; int rem = i - o*768;
  int tap = rem >> 8; int ch = rem & 255;
  w2h[i]  = (_Float16)w2[o*768 + ch*3 + tap];
  wihh[i] = (_Float16)wih[i];
  if (i < 256*32) {
    int oo = i >> 5, k = i & 31;
    float v = 0.f;
    if (k < 9) { int tp = k/3, ic = k - 3*tp; v = w1[oo*9 + ic*3 + tp]; }
    w1h[i] = (_Float16)v;
  }
}

// ---------------- fused rotate + conv1(MFMA) + conv2(MFMA) + mean + gx(MFMA) ----------------
__launch_bounds__(256, 2)
__global__ void k_conv(const float* __restrict__ traj, const int* __restrict__ offs,
                       const int* __restrict__ rmod,
                       const float* __restrict__ cB, const float* __restrict__ sB,
                       const float* __restrict__ oxB, const float* __restrict__ oyB,
                       const float* __restrict__ hdB,
                       const float* __restrict__ b1, const float* __restrict__ b2,
                       const float* __restrict__ bih, const float* __restrict__ bhh,
                       const _Float16* __restrict__ w1h,
                       const _Float16* __restrict__ w2h,
                       const _Float16* __restrict__ wihh,
                       _Float16* __restrict__ gx, int N)
{
  __shared__ __align__(16) union {
    _Float16 y1p[16][7][264];                  // 59,136 B (rows w=0 / w=6 are zero pads)
    _Float16 sY2[80][264];                     // 42,240 B (post-conv2, pre-mean)
  } U;
  __shared__ __align__(16) union {
    _Float16 sA[80][32];                       // conv1 A-tile (early)
    _Float16 arb[16][264];                     // mean result f16 (late)
  } V;
  __shared__ float xls[16][5][3];
  __shared__ int   segB[16], segT0[16];
  __shared__ float segC[16], segS[16], segOx[16], segOy[16], segHd[16];

  const int tid = threadIdx.x;
  const int n0  = blockIdx.x * 16;
  const int cnt = min(16, N - n0);

  // zero only the pad rows of y1p: [s][0][*] and [s][6][*]  (1056 uint4)
  for (int i = tid; i < 1056; i += 256) {
    int s = i / 66, r = i - s*66;
    int wq = (r < 33) ? 0 : 6, c8 = (r < 33) ? r : r - 33;
    *(uint4*)&U.y1p[s][wq][c8*8] = make_uint4(0,0,0,0);
  }

  if (tid < 16) {
    int n = n0 + min(tid, cnt-1);
    int lo=0, hi=NB-1;
    while (lo < hi) { int mid=(lo+hi+1)>>1; if (offs[mid] <= n) lo=mid; else hi=mid-1; }
    int b = lo; int k = n - offs[b];
    segB[tid]=b; segT0[tid]= rmod[b] + STEPW*k;
    segC[tid]=cB[b]; segS[tid]=sB[b]; segOx[tid]=oxB[b]; segOy[tid]=oyB[b]; segHd[tid]=hdB[b];
  }
  __syncthreads();

  // rotate the 16x5 window points
  if (tid < 80) {
    int s = tid/5, w = tid%5;
    int b = segB[s]; int t = segT0[s] + w;
    const float* p = traj + ((size_t)b*TT + (size_t)t)*3;
    float X=p[0], Y=p[1], A=p[2];
    float dx = X - segOx[s], dy = Y - segOy[s];
    float c = segC[s], sn = segS[s];
    float ang = fmodf(A + segHd[s] + 720.0f, 360.0f) * D2R;
    if (ang > PI_F) ang -= 2.0f*PI_F;
    xls[s][w][0] = c*dx - sn*dy;
    xls[s][w][1] = sn*dx + c*dy;
    xls[s][w][2] = ang;
  }
  __syncthreads();

  // fill conv1 A-tile: sA[row=(s*5+w)][k=tap*3+inch] = xls[s][w+tap-1][inch] (0-padded)
  for (int u = 0; u < 10; u++) {
    int e = u*256 + tid;                 // 2560 elems
    int row = e >> 5, k = e & 31;
    float v = 0.f;
    if (k < 9) {
      int tp = k/3, ic = k - 3*tp;
      int s = row/5, w = row - 5*s;
      int wp = w + tp - 1;
      if (wp >= 0 && wp < 5) v = xls[s][wp][ic];
    }
    V.sA[0][e] = (_Float16)v;
  }
  __syncthreads();

  const int wv_  = tid >> 6;          // wave 0..3
  const int lane = tid & 63;
  const int m = lane & 15, q = lane >> 4;

  // conv1 as MFMA: M=80 rows, N=256 ch, K=32 (only 9 live)
  {
    f32x4 c1[5][4];
    #pragma unroll
    for (int a=0;a<5;a++) for (int bq=0;bq<4;bq++) c1[a][bq] = (f32x4){0.f,0.f,0.f,0.f};
    f16x8 bfr[4];
    #pragma unroll
    for (int nn=0;nn<4;nn++) {
      int col = (wv_*4+nn)*16 + m;
      bfr[nn] = *(const f16x8*)(w1h + col*32 + q*8);
    }
    #pragma unroll
    for (int mt=0; mt<5; mt++) {
      f16x8 afr = *(const f16x8*)&V.sA[mt*16 + m][q*8];
      #pragma unroll
      for (int nn=0;nn<4;nn++)
        c1[mt][nn] = __builtin_amdgcn_mfma_f32_16x16x32_f16(afr, bfr[nn], c1[mt][nn], 0,0,0);
    }
    // epilogue: relu(+b1) -> y1p rows 1..5
    #pragma unroll
    for (int nn=0;nn<4;nn++){
      int col = (wv_*4+nn)*16 + m;
      float bb = b1[col];
      #pragma unroll
      for (int mt=0;mt<5;mt++){
        #pragma unroll
        for (int v=0;v<4;v++){
          int row = mt*16 + q*4 + v;       // 0..79
          int s = row/5, w = row - 5*s;
          U.y1p[s][w+1][col] = (_Float16)fmaxf(c1[mt][nn][v] + bb, 0.f);
        }
      }
    }
  }
  __syncthreads();

  // conv2 as GEMM: rows=(s,w) 80, cols=256, K=768=(tap,ch)
  f32x4 acc[5][4];
  #pragma unroll
  for (int a=0;a<5;a++) for (int bq=0;bq<4;bq++) acc[a][bq] = (f32x4){0.f,0.f,0.f,0.f};
  int segi[5], wwi[5];
  #pragma unroll
  for (int mt=0; mt<5; mt++){ int row = mt*16+m; segi[mt]=row/5; wwi[mt]=row%5; }

  for (int ks=0; ks<24; ks++) {
    int tap = ks >> 3, ch0 = (ks & 7)*32 + q*8;
    f16x8 afr[5];
    #pragma unroll
    for (int mt=0; mt<5; mt++)
      afr[mt] = *(const f16x8*)&U.y1p[segi[mt]][wwi[mt]+tap][ch0];
    #pragma unroll
    for (int nn=0; nn<4; nn++) {
      int col = (wv_*4+nn)*16 + m;
      f16x8 bfr = *(const f16x8*)(w2h + (size_t)col*768 + tap*256 + (ks&7)*32 + q*8);
      #pragma unroll
      for (int mt=0; mt<5; mt++)
        acc[mt][nn] = __builtin_amdgcn_mfma_f32_16x16x32_f16(afr[mt], bfr, acc[mt][nn], 0,0,0);
    }
  }
  __syncthreads();   // all conv2 reads of y1p done; union region becomes sY2

  // stage relu(y2 + b2) as f16
  #pragma unroll
  for (int nn=0;nn<4;nn++){
    int col = (wv_*4+nn)*16 + m;
    float bb = b2[col];
    #pragma unroll
    for (int mt=0;mt<5;mt++){
      #pragma unroll
      for (int v=0;v<4;v++){
        int row = mt*16 + q*4 + v;
        U.sY2[row][col] = (_Float16)fmaxf(acc[mt][nn][v] + bb, 0.f);
      }
    }
  }
  __syncthreads();

  // mean over w: arb[s][c] = 0.2 * sum_w sY2[5s+w][c]
  for (int s=0; s<16; s++) {
    float sum = 0.f;
    #pragma unroll
    for (int w=0;w<5;w++) sum += (float)U.sY2[5*s+w][tid];
    V.arb[s][tid] = (_Float16)(sum*0.2f);
  }
  __syncthreads();

  // gx GEMM: M=16 segs, N=768 gates, K=256 ; fold (bih [+bhh]) into gx
  f32x4 acc2[12];
  #pragma unroll
  for (int a=0;a<12;a++) acc2[a] = (f32x4){0.f,0.f,0.f,0.f};
  #pragma unroll
  for (int ks=0; ks<8; ks++) {
    int ch0 = ks*32 + q*8;
    f16x8 afr = *(const f16x8*)&V.arb[m][ch0];
    #pragma unroll
    for (int nn=0; nn<12; nn++) {
      int col = (wv_*12+nn)*16 + m;
      f16x8 bfr = *(const f16x8*)(wihh + (size_t)col*256 + ch0);
      acc2[nn] = __builtin_amdgcn_mfma_f32_16x16x32_f16(afr, bfr, acc2[nn], 0,0,0);
    }
  }
  #pragma unroll
  for (int nn=0; nn<12; nn++){
    int col = (wv_*12+nn)*16 + m;
    float bias = bih[col] + (col < 512 ? bhh[col] : 0.f);
    #pragma unroll
    for (int v=0; v<4; v++){
      int row = q*4 + v;            // seg index within block
      if (row < cnt)
        gx[(size_t)(n0+row)*G3 + col] = (_Float16)(acc2[nn][v] + bias);
    }
  }
}

// ---------------- GRU recurrence: 1 block/sample, W in VGPRs, K split 4-ways ----------------
// wave w: kq = w&3 (K slice of 64), rg = w>>2 (row group of 256).
// thread: rows rg*256 + 64*i + lane (i=0..3), K in [kq*64, kq*64+64).
__launch_bounds__(768, 3)
__global__ void k_gru(const _Float16* __restrict__ gx,
                      const float* __restrict__ whh,
                      const float* __restrict__ bhh,
                      const int* __restrict__ offs, float* __restrict__ out)
{
  __shared__ float sPart[4][G3];                   // [kq][row] partials, conflict-free
  __shared__ __align__(16) unsigned int hb[HH/2];  // h as packed f16 pairs

  const int tid  = threadIdx.x;
  const int lane = tid & 63;
  const int wv   = tid >> 6;
  const int kq   = wv & 3;
  const int rg   = wv >> 2;
  const int b    = blockIdx.x;
  const int base = offs[b];
  const int segs = offs[b+1] - base;

  // pack own W slice: 4 rows x 64 K -> 128 packed-pair dwords (must stay in VGPRs)
  unsigned int wpk[4][32];
  #pragma unroll
  for (int i=0;i<4;i++){
    const float4* wr = (const float4*)(whh + (size_t)(rg*256 + 64*i + lane)*256 + kq*64);
    #pragma unroll
    for (int c=0;c<16;c++){
      float4 v = wr[c];
      wpk[i][2*c]   = pack_f16(v.x, v.y);
      wpk[i][2*c+1] = pack_f16(v.z, v.w);
    }
  }

  const bool gate = (tid < HH);
  const float bhh2 = gate ? bhh[512+tid] : 0.f;
  float hprev = 0.f;

  if (tid < HH/2) hb[tid] = 0u;
  __syncthreads();

  // preload gx row 0 (biases already folded in by k_conv)
  float gr=0.f, gz=0.f, gn=0.f;
  if (gate) {
    const _Float16* g0 = gx + (size_t)base*G3;
    gr = (float)g0[tid]; gz = (float)g0[256+tid]; gn = (float)g0[512+tid];
  }

  for (int j=0; j<segs; j++) {
    // next-step gx prefetch (hidden under the dot chain + barriers)
    float pr=0.f, pz=0.f, pn=0.f;
    if (gate) {
      int jn = (j+1 < segs) ? j+1 : j;
      const _Float16* g1 = gx + (size_t)(base+jn)*G3;
      pr = (float)g1[tid]; pz = (float)g1[256+tid]; pn = (float)g1[512+tid];
    }

    // 4 rows x 64 K of dot2 against wave-uniform h slice (8 broadcast b128 reads)
    float a0=0.f, a1=0.f, a2=0.f, a3=0.f;
    const uint4* h4 = (const uint4*)(hb + kq*32);
    #pragma unroll
    for (int c8=0;c8<8;c8++){
      uint4 hv = h4[c8];
      #pragma unroll
      for (int t2=0;t2<4;t2++){
        unsigned int hvv = (&hv.x)[t2];
        int c = 4*c8 + t2;
        a0 = dot2h(hvv, wpk[0][c], a0);
        a1 = dot2h(hvv, wpk[1][c], a1);
        a2 = dot2h(hvv, wpk[2][c], a2);
        a3 = dot2h(hvv, wpk[3][c], a3);
      }
    }
    sPart[kq][rg*256 +        lane] = a0;
    sPart[kq][rg*256 +  64 +  lane] = a1;
    sPart[kq][rg*256 + 128 +  lane] = a2;
    sPart[kq][rg*256 + 192 +  lane] = a3;
    __syncthreads();

    if (gate) {
      float hr = sPart[0][tid]     + sPart[1][tid]     + sPart[2][tid]     + sPart[3][tid];
      float hz = sPart[0][256+tid] + sPart[1][256+tid] + sPart[2][256+tid] + sPart[3][256+tid];
      float hn = sPart[0][512+tid] + sPart[1][512+tid] + sPart[2][512+tid] + sPart[3][512+tid];
      float r = 1.f/(1.f + __expf(-(gr + hr)));
      float z = 1.f/(1.f + __expf(-(gz + hz)));
      float pre = gn + r*(hn + bhh2);
      float e2 = __expf(2.f*pre);
      float n = 1.f - 2.f/(e2 + 1.f);            // tanh
      float hnew = (1.f - z)*n + z*hprev;
      hprev = hnew;
      ((_Float16*)hb)[tid] = (_Float16)hnew;
      out[(size_t)(base + j)*HH + tid] = hnew;
    }
    __syncthreads();
    gr = pr; gz = pz; gn = pn;
  }
}

extern "C" void kernel_launch(void* const* d_in, const int* in_sizes, int n_in,
                              void* d_out, int out_size, void* d_ws, size_t ws_size,
                              hipStream_t stream)
{
  const float* traj = (const float*)d_in[0];
  const int*   lens = (const int*)d_in[1];
  const float* w1   = (const float*)d_in[2];
  const float* b1   = (const float*)d_in[3];
  const float* w2   = (const float*)d_in[4];
  const float* b2   = (const float*)d_in[5];
  const float* wih  = (const float*)d_in[6];
  const float* whh  = (const float*)d_in[7];
  const float* bih  = (const float*)d_in[8];
  const float* bhh  = (const float*)d_in[9];
  float* out = (float*)d_out;
  const int N = out_size / HH;

  char* ws = (char*)d_ws;
  int*   offs = (int*)(ws + 0);          // 129 ints
  int*   rmod = (int*)(ws + 1024);
  float* cB   = (float*)(ws + 2048);
  float* sB   = (float*)(ws + 2560);
  float* oxB  = (float*)(ws + 3072);
  float* oyB  = (float*)(ws + 3584);
  float* hdB  = (float*)(ws + 4096);
  _Float16* w1h  = (_Float16*)(ws + 8192);                 // 256*32*2   = 16,384
  _Float16* w2h  = (_Float16*)(ws + 24576);                // 196608*2   = 393,216
  _Float16* wihh = (_Float16*)(ws + 24576 + 393216);       // 393,216
  _Float16* gx   = (_Float16*)(ws + 24576 + 2*393216);     // N x 768 f16

  k_setup<<<1, 128, 0, stream>>>(traj, lens, offs, rmod, cB, sB, oxB, oyB, hdB);
  k_prep<<<768, 256, 0, stream>>>(w2, wih, w1, w2h, wihh, w1h);
  k_conv<<<(N+15)/16, 256, 0, stream>>>(traj, offs, rmod, cB, sB, oxB, oyB, hdB,
                                        b1, b2, bih, bhh, w1h, w2h, wihh, gx, N);
  k_gru<<<NB, 768, 0, stream>>>(gx, whh, bhh, offs, out);
}

// Round 4
// 1481.652 us; speedup vs baseline: 1.4472x; 1.0834x over previous
//
#include <hip/hip_runtime.h>
#include <hip/hip_bf16.h>
#include <hip/hip_fp16.h>

#define NB 128
#define TT 4096
#define HH 256
#define G3 768
#define STEPW 5
#define PI_F 3.14159265358979323846f
#define D2R  0.017453292519943295f

typedef _Float16 f16x8 __attribute__((ext_vector_type(8)));
typedef _Float16 f16x2 __attribute__((ext_vector_type(2)));
typedef float f32x4 __attribute__((ext_vector_type(4)));

__device__ __forceinline__ unsigned int pack_f16(float x, float y){
  union { f16x2 h; unsigned int u; } cv;
  cv.h = (f16x2){(_Float16)x, (_Float16)y};
  return cv.u;
}

// f32 += f16x2 . f16x2  (v_dot2_f32_f16)
__device__ __forceinline__ float dot2h(unsigned int a, unsigned int b, float c){
  union { unsigned int u; f16x2 h; } ua, ub;
  ua.u = a; ub.u = b;
  return __builtin_amdgcn_fdot2(ua.h, ub.h, c, false);
}

// ---------------- setup: per-sample params + prefix sum ----------------
__global__ void k_setup(const float* __restrict__ traj, const int* __restrict__ lens,
                        int* offs, int* rmod, float* cB, float* sB,
                        float* oxB, float* oyB, float* hdB){
  __shared__ int sl[NB];
  int b = threadIdx.x;
  if (b < NB) {
    int L = lens[b];
    rmod[b] = L % STEPW;
    sl[b] = L / STEPW;
    const float* last = traj + ((size_t)b*TT + (size_t)(L-1))*3;
    float ox = last[0], oy = last[1], hd = -last[2];
    float th = hd * D2R;
    cB[b] = cosf(th); sB[b] = sinf(th);
    oxB[b]=ox; oyB[b]=oy; hdB[b]=hd;
  }
  __syncthreads();
  if (threadIdx.x == 0) {
    int acc = 0;
    for (int i=0;i<NB;i++){ offs[i]=acc; acc += sl[i]; }
    offs[NB]=acc;
  }
}

// ---------------- prep: f16 weight repacks ----------------
// w2h[o][tap][ch] = w2[o][ch][tap]; wihh[g][ch] = w_ih[g][ch];
// w1h[o][k] : k = tap*3+inch (k<9), zero-padded to 32.
// whhp: per-thread pre-packed W_hh for k_gru (thread tid owns dwords tid*128..+127,
//        dword i*32+c = pack(whh[row(i)][kq*64+2c], ...+2c+1)), row(i)=rg*256+64*i+lane.
__global__ void k_prep(const float* __restrict__ w2, const float* __restrict__ wih,
                       const float* __restrict__ w1, const float* __restrict__ whh,
                       _Float16* w2h, _Float16* wihh, _Float16* w1h,
                       unsigned int* whhp){
  int i = blockIdx.x*256 + threadIdx.x;      // 0 .. 196607
  int o = i / 768; int rem = i - o*768;
  int tap = rem >> 8; int ch = rem & 255;
  w2h[i]  = (_Float16)w2[o*768 + ch*3 + tap];
  wihh[i] = (_Float16)wih[i];
  if (i < 256*32) {
    int oo = i >> 5, k = i & 31;
    float v = 0.f;
    if (k < 9) { int tp = k/3, ic = k - 3*tp; v = w1[oo*9 + ic*3 + tp]; }
    w1h[i] = (_Float16)v;
  }
  if (i < 98304) {
    int tid = i >> 7, r7 = i & 127;
    int ii = r7 >> 5, c = r7 & 31;
    int lane = tid & 63, wvv = tid >> 6;
    int kq = wvv & 3, rg = wvv >> 2;
    int row = rg*256 + 64*ii + lane;
    int kk = kq*64 + 2*c;
    whhp[i] = pack_f16(whh[row*256 + kk], whh[row*256 + kk + 1]);
  }
}

// ---------------- fused rotate + conv1(MFMA) + conv2(MFMA) + mean + gx(MFMA) ----------------
__launch_bounds__(256, 2)
__global__ void k_conv(const float* __restrict__ traj, const int* __restrict__ offs,
                       const int* __restrict__ rmod,
                       const float* __restrict__ cB, const float* __restrict__ sB,
                       const float* __restrict__ oxB, const float* __restrict__ oyB,
                       const float* __restrict__ hdB,
                       const float* __restrict__ b1, const float* __restrict__ b2,
                       const float* __restrict__ bih, const float* __restrict__ bhh,
                       const _Float16* __restrict__ w1h,
                       const _Float16* __restrict__ w2h,
                       const _Float16* __restrict__ wihh,
                       _Float16* __restrict__ gx, int N)
{
  __shared__ __align__(16) union {
    _Float16 y1p[16][7][264];                  // 59,136 B (rows w=0 / w=6 are zero pads)
    _Float16 sY2[80][264];                     // 42,240 B (post-conv2, pre-mean)
  } U;
  __shared__ __align__(16) union {
    _Float16 sA[80][32];                       // conv1 A-tile (early)
    _Float16 arb[16][264];                     // mean result f16 (late)
  } V;
  __shared__ float xls[16][5][3];
  __shared__ int   segB[16], segT0[16];
  __shared__ float segC[16], segS[16], segOx[16], segOy[16], segHd[16];

  const int tid = threadIdx.x;
  const int n0  = blockIdx.x * 16;
  const int cnt = min(16, N - n0);

  // zero only the pad rows of y1p: [s][0][*] and [s][6][*]  (1056 uint4)
  for (int i = tid; i < 1056; i += 256) {
    int s = i / 66, r = i - s*66;
    int wq = (r < 33) ? 0 : 6, c8 = (r < 33) ? r : r - 33;
    *(uint4*)&U.y1p[s][wq][c8*8] = make_uint4(0,0,0,0);
  }

  if (tid < 16) {
    int n = n0 + min(tid, cnt-1);
    int lo=0, hi=NB-1;
    while (lo < hi) { int mid=(lo+hi+1)>>1; if (offs[mid] <= n) lo=mid; else hi=mid-1; }
    int b = lo; int k = n - offs[b];
    segB[tid]=b; segT0[tid]= rmod[b] + STEPW*k;
    segC[tid]=cB[b]; segS[tid]=sB[b]; segOx[tid]=oxB[b]; segOy[tid]=oyB[b]; segHd[tid]=hdB[b];
  }
  __syncthreads();

  // rotate the 16x5 window points
  if (tid < 80) {
    int s = tid/5, w = tid%5;
    int b = segB[s]; int t = segT0[s] + w;
    const float* p = traj + ((size_t)b*TT + (size_t)t)*3;
    float X=p[0], Y=p[1], A=p[2];
    float dx = X - segOx[s], dy = Y - segOy[s];
    float c = segC[s], sn = segS[s];
    float ang = fmodf(A + segHd[s] + 720.0f, 360.0f) * D2R;
    if (ang > PI_F) ang -= 2.0f*PI_F;
    xls[s][w][0] = c*dx - sn*dy;
    xls[s][w][1] = sn*dx + c*dy;
    xls[s][w][2] = ang;
  }
  __syncthreads();

  // fill conv1 A-tile: sA[row=(s*5+w)][k=tap*3+inch] = xls[s][w+tap-1][inch] (0-padded)
  for (int u = 0; u < 10; u++) {
    int e = u*256 + tid;                 // 2560 elems
    int row = e >> 5, k = e & 31;
    float v = 0.f;
    if (k < 9) {
      int tp = k/3, ic = k - 3*tp;
      int s = row/5, w = row - 5*s;
      int wp = w + tp - 1;
      if (wp >= 0 && wp < 5) v = xls[s][wp][ic];
    }
    V.sA[0][e] = (_Float16)v;
  }
  __syncthreads();

  const int wv_  = tid >> 6;          // wave 0..3
  const int lane = tid & 63;
  const int m = lane & 15, q = lane >> 4;

  // conv1 as MFMA: M=80 rows, N=256 ch, K=32 (only 9 live)
  {
    f32x4 c1[5][4];
    #pragma unroll
    for (int a=0;a<5;a++) for (int bq=0;bq<4;bq++) c1[a][bq] = (f32x4){0.f,0.f,0.f,0.f};
    f16x8 bfr[4];
    #pragma unroll
    for (int nn=0;nn<4;nn++) {
      int col = (wv_*4+nn)*16 + m;
      bfr[nn] = *(const f16x8*)(w1h + col*32 + q*8);
    }
    #pragma unroll
    for (int mt=0; mt<5; mt++) {
      f16x8 afr = *(const f16x8*)&V.sA[mt*16 + m][q*8];
      #pragma unroll
      for (int nn=0;nn<4;nn++)
        c1[mt][nn] = __builtin_amdgcn_mfma_f32_16x16x32_f16(afr, bfr[nn], c1[mt][nn], 0,0,0);
    }
    // epilogue: relu(+b1) -> y1p rows 1..5
    #pragma unroll
    for (int nn=0;nn<4;nn++){
      int col = (wv_*4+nn)*16 + m;
      float bb = b1[col];
      #pragma unroll
      for (int mt=0;mt<5;mt++){
        #pragma unroll
        for (int v=0;v<4;v++){
          int row = mt*16 + q*4 + v;       // 0..79
          int s = row/5, w = row - 5*s;
          U.y1p[s][w+1][col] = (_Float16)fmaxf(c1[mt][nn][v] + bb, 0.f);
        }
      }
    }
  }
  __syncthreads();

  // conv2 as GEMM: rows=(s,w) 80, cols=256, K=768=(tap,ch); B loads software-pipelined
  f32x4 acc[5][4];
  #pragma unroll
  for (int a=0;a<5;a++) for (int bq=0;bq<4;bq++) acc[a][bq] = (f32x4){0.f,0.f,0.f,0.f};
  int segi[5], wwi[5];
  #pragma unroll
  for (int mt=0; mt<5; mt++){ int row = mt*16+m; segi[mt]=row/5; wwi[mt]=row%5; }

  f16x8 bcur[4];
  #pragma unroll
  for (int nn=0;nn<4;nn++) {
    int col = (wv_*4+nn)*16 + m;
    bcur[nn] = *(const f16x8*)(w2h + (size_t)col*768 + q*8);     // ks=0
  }
  for (int ks=0; ks<24; ks++) {
    int tap = ks >> 3, ch0 = (ks & 7)*32 + q*8;
    // prefetch next-ks B fragments (global, L2-resident) before using current
    f16x8 bnext[4];
    int ksn = (ks+1 < 24) ? ks+1 : ks;
    int kofN = (ksn >> 3)*256 + (ksn & 7)*32 + q*8;
    #pragma unroll
    for (int nn=0;nn<4;nn++) {
      int col = (wv_*4+nn)*16 + m;
      bnext[nn] = *(const f16x8*)(w2h + (size_t)col*768 + kofN);
    }
    f16x8 afr[5];
    #pragma unroll
    for (int mt=0; mt<5; mt++)
      afr[mt] = *(const f16x8*)&U.y1p[segi[mt]][wwi[mt]+tap][ch0];
    #pragma unroll
    for (int nn=0; nn<4; nn++)
      #pragma unroll
      for (int mt=0; mt<5; mt++)
        acc[mt][nn] = __builtin_amdgcn_mfma_f32_16x16x32_f16(afr[mt], bcur[nn], acc[mt][nn], 0,0,0);
    #pragma unroll
    for (int nn=0;nn<4;nn++) bcur[nn] = bnext[nn];
  }
  __syncthreads();   // all conv2 reads of y1p done; union region becomes sY2

  // stage relu(y2 + b2) as f16
  #pragma unroll
  for (int nn=0;nn<4;nn++){
    int col = (wv_*4+nn)*16 + m;
    float bb = b2[col];
    #pragma unroll
    for (int mt=0;mt<5;mt++){
      #pragma unroll
      for (int v=0;v<4;v++){
        int row = mt*16 + q*4 + v;
        U.sY2[row][col] = (_Float16)fmaxf(acc[mt][nn][v] + bb, 0.f);
      }
    }
  }
  __syncthreads();

  // mean over w: arb[s][c] = 0.2 * sum_w sY2[5s+w][c]
  for (int s=0; s<16; s++) {
    float sum = 0.f;
    #pragma unroll
    for (int w=0;w<5;w++) sum += (float)U.sY2[5*s+w][tid];
    V.arb[s][tid] = (_Float16)(sum*0.2f);
  }
  __syncthreads();

  // gx GEMM: M=16 segs, N=768 gates, K=256 ; fold (bih [+bhh]) into gx; B pipelined
  f32x4 acc2[12];
  #pragma unroll
  for (int a=0;a<12;a++) acc2[a] = (f32x4){0.f,0.f,0.f,0.f};
  f16x8 bcur2[12];
  #pragma unroll
  for (int nn=0;nn<12;nn++) {
    int col = (wv_*12+nn)*16 + m;
    bcur2[nn] = *(const f16x8*)(wihh + (size_t)col*256 + q*8);
  }
  #pragma unroll
  for (int ks=0; ks<8; ks++) {
    int ch0 = ks*32 + q*8;
    f16x8 bnext2[12];
    int ksn = (ks+1 < 8) ? ks+1 : ks;
    #pragma unroll
    for (int nn=0;nn<12;nn++) {
      int col = (wv_*12+nn)*16 + m;
      bnext2[nn] = *(const f16x8*)(wihh + (size_t)col*256 + ksn*32 + q*8);
    }
    f16x8 afr = *(const f16x8*)&V.arb[m][ch0];
    #pragma unroll
    for (int nn=0; nn<12; nn++)
      acc2[nn] = __builtin_amdgcn_mfma_f32_16x16x32_f16(afr, bcur2[nn], acc2[nn], 0,0,0);
    #pragma unroll
    for (int nn=0;nn<12;nn++) bcur2[nn] = bnext2[nn];
  }
  #pragma unroll
  for (int nn=0; nn<12; nn++){
    int col = (wv_*12+nn)*16 + m;
    float bias = bih[col] + (col < 512 ? bhh[col] : 0.f);
    #pragma unroll
    for (int v=0; v<4; v++){
      int row = q*4 + v;            // seg index within block
      if (row < cnt)
        gx[(size_t)(n0+row)*G3 + col] = (_Float16)(acc2[nn][v] + bias);
    }
  }
}

// ---------------- GRU recurrence: 1 block/sample, W in VGPRs, K split 4-ways ----------------
// wave w: kq = w&3 (K slice of 64), rg = w>>2 (row group of 256).
// thread: rows rg*256 + 64*i + lane (i=0..3), K in [kq*64, kq*64+64).
// waves_per_eu(3,3): pin allocator target to 3 waves/EU (170-reg budget) so the
// 128-dword W array stays in VGPRs (round-3: target 6 -> 84 regs -> scratch spill).
__global__ void __attribute__((amdgpu_flat_work_group_size(768, 768), amdgpu_waves_per_eu(3, 3)))
k_gru(const _Float16* __restrict__ gx,
      const unsigned int* __restrict__ whhp,
      const float* __restrict__ bhh,
      const int* __restrict__ offs, float* __restrict__ out)
{
  __shared__ float sPart[4][G3];                   // [kq][row] partials, conflict-free
  __shared__ __align__(16) unsigned int hb[HH/2];  // h as packed f16 pairs

  const int tid  = threadIdx.x;
  const int lane = tid & 63;
  const int wv   = tid >> 6;
  const int kq   = wv & 3;
  const int rg   = wv >> 2;
  const int b    = blockIdx.x;
  const int base = offs[b];
  const int segs = offs[b+1] - base;

  // own pre-packed W slice: 32 dwordx4 loads, must stay resident in VGPRs
  uint4 wq4[32];
  {
    const uint4* wp = (const uint4*)whhp + (size_t)tid*32;
    #pragma unroll
    for (int c4=0;c4<32;c4++) wq4[c4] = wp[c4];
  }

  const bool gate = (tid < HH);
  const float bhh2 = gate ? bhh[512+tid] : 0.f;
  float hprev = 0.f;

  if (tid < HH/2) hb[tid] = 0u;
  __syncthreads();

  // preload gx row 0 (biases already folded in by k_conv)
  float gr=0.f, gz=0.f, gn=0.f;
  if (gate) {
    const _Float16* g0 = gx + (size_t)base*G3;
    gr = (float)g0[tid]; gz = (float)g0[256+tid]; gn = (float)g0[512+tid];
  }

  for (int j=0; j<segs; j++) {
    // next-step gx prefetch (hidden under the dot chain + barriers)
    float pr=0.f, pz=0.f, pn=0.f;
    if (gate) {
      int jn = (j+1 < segs) ? j+1 : j;
      const _Float16* g1 = gx + (size_t)(base+jn)*G3;
      pr = (float)g1[tid]; pz = (float)g1[256+tid]; pn = (float)g1[512+tid];
    }

    // 4 rows x 64 K of dot2 against wave-uniform h slice (8 broadcast b128 reads)
    float a0=0.f, a1=0.f, a2=0.f, a3=0.f;
    const uint4* h4 = (const uint4*)(hb + kq*32);
    #pragma unroll
    for (int c8=0;c8<8;c8++){
      uint4 hv = h4[c8];
      uint4 w0 = wq4[c8], w1 = wq4[8+c8], w2 = wq4[16+c8], w3 = wq4[24+c8];
      #pragma unroll
      for (int t2=0;t2<4;t2++){
        unsigned int hvv = (&hv.x)[t2];
        a0 = dot2h(hvv, (&w0.x)[t2], a0);
        a1 = dot2h(hvv, (&w1.x)[t2], a1);
        a2 = dot2h(hvv, (&w2.x)[t2], a2);
        a3 = dot2h(hvv, (&w3.x)[t2], a3);
      }
    }
    sPart[kq][rg*256 +        lane] = a0;
    sPart[kq][rg*256 +  64 +  lane] = a1;
    sPart[kq][rg*256 + 128 +  lane] = a2;
    sPart[kq][rg*256 + 192 +  lane] = a3;
    __syncthreads();

    if (gate) {
      float hr = sPart[0][tid]     + sPart[1][tid]     + sPart[2][tid]     + sPart[3][tid];
      float hz = sPart[0][256+tid] + sPart[1][256+tid] + sPart[2][256+tid] + sPart[3][256+tid];
      float hn = sPart[0][512+tid] + sPart[1][512+tid] + sPart[2][512+tid] + sPart[3][512+tid];
      float r = 1.f/(1.f + __expf(-(gr + hr)));
      float z = 1.f/(1.f + __expf(-(gz + hz)));
      float pre = gn + r*(hn + bhh2);
      float e2 = __expf(2.f*pre);
      float n = 1.f - 2.f/(e2 + 1.f);            // tanh
      float hnew = (1.f - z)*n + z*hprev;
      hprev = hnew;
      ((_Float16*)hb)[tid] = (_Float16)hnew;
      out[(size_t)(base + j)*HH + tid] = hnew;
    }
    __syncthreads();
    gr = pr; gz = pz; gn = pn;
  }
}

extern "C" void kernel_launch(void* const* d_in, const int* in_sizes, int n_in,
                              void* d_out, int out_size, void* d_ws, size_t ws_size,
                              hipStream_t stream)
{
  const float* traj = (const float*)d_in[0];
  const int*   lens = (const int*)d_in[1];
  const float* w1   = (const float*)d_in[2];
  const float* b1   = (const float*)d_in[3];
  const float* w2   = (const float*)d_in[4];
  const float* b2   = (const float*)d_in[5];
  const float* wih  = (const float*)d_in[6];
  const float* whh  = (const float*)d_in[7];
  const float* bih  = (const float*)d_in[8];
  const float* bhh  = (const float*)d_in[9];
  float* out = (float*)d_out;
  const int N = out_size / HH;

  char* ws = (char*)d_ws;
  int*   offs = (int*)(ws + 0);          // 129 ints
  int*   rmod = (int*)(ws + 1024);
  float* cB   = (float*)(ws + 2048);
  float* sB   = (float*)(ws + 2560);
  float* oxB  = (float*)(ws + 3072);
  float* oyB  = (float*)(ws + 3584);
  float* hdB  = (float*)(ws + 4096);
  _Float16*     w1h  = (_Float16*)(ws + 8192);                   // 16,384 B
  _Float16*     w2h  = (_Float16*)(ws + 24576);                  // 393,216 B
  _Float16*     wihh = (_Float16*)(ws + 24576 + 393216);         // 393,216 B
  unsigned int* whhp = (unsigned int*)(ws + 24576 + 2*393216);   // 393,216 B
  _Float16*     gx   = (_Float16*)(ws + 24576 + 3*393216);       // N x 768 f16

  k_setup<<<1, 128, 0, stream>>>(traj, lens, offs, rmod, cB, sB, oxB, oyB, hdB);
  k_prep<<<768, 256, 0, stream>>>(w2, wih, w1, whh, w2h, wihh, w1h, whhp);
  k_conv<<<(N+15)/16, 256, 0, stream>>>(traj, offs, rmod, cB, sB, oxB, oyB, hdB,
                                        b1, b2, bih, bhh, w1h, w2h, wihh, gx, N);
  k_gru<<<NB, 768, 0, stream>>>(gx, whhp, bhh, offs, out);
}